// Round 7
// baseline (960.202 us; speedup 1.0000x reference)
//
#include <hip/hip_runtime.h>
#include <hip/hip_bf16.h>

#define N_NODES 100000
#define N_EDGES 1600000
#define N_GRAPHS 1024
#define F_NODE 16
#define F_EDGE 8
#define F_GRAPH 10
#define HD 64
#define HD2 128
#define GEN_EPS 1e-7f
#define SCAN_NBLK ((N_NODES + 255) / 256)   // 391

// h[n][f] = node_b[f] + sum_k x[n][k]*node_W[k][f]
__global__ void __launch_bounds__(256) k_node_embed(
        const float* __restrict__ x, const float* __restrict__ W,
        const float* __restrict__ b, float* __restrict__ h) {
    __shared__ float sW[F_NODE * HD];
    __shared__ float sb[HD];
    for (int i = threadIdx.x; i < F_NODE * HD; i += 256) sW[i] = W[i];
    if (threadIdx.x < HD) sb[threadIdx.x] = b[threadIdx.x];
    __syncthreads();
    int t = blockIdx.x * 256 + threadIdx.x;
    if (t >= N_NODES * HD) return;
    int n = t >> 6, f = t & 63;
    const float* xr = x + (size_t)n * F_NODE;
    float acc = sb[f];
#pragma unroll
    for (int k = 0; k < F_NODE; k++) acc += xr[k] * sW[k * HD + f];
    h[t] = acc;
}

// ---- CSR build (once per launch, reused by all 3 conv layers) ----
__global__ void __launch_bounds__(256) k_hist(
        const int* __restrict__ dst, int* __restrict__ deg) {
    int e = blockIdx.x * 256 + threadIdx.x;
    if (e >= N_EDGES) return;
    atomicAdd(&deg[dst[e]], 1);
}

// Parallel exclusive scan, 3 phases.
__global__ void __launch_bounds__(256) k_scan1(
        const int* __restrict__ deg, int* __restrict__ bsum) {
    __shared__ int red[256];
    int t = threadIdx.x;
    int g = blockIdx.x * 256 + t;
    red[t] = (g < N_NODES) ? deg[g] : 0;
    __syncthreads();
    for (int s = 128; s > 0; s >>= 1) {
        if (t < s) red[t] += red[t + s];
        __syncthreads();
    }
    if (t == 0) bsum[blockIdx.x] = red[0];
}

__global__ void __launch_bounds__(512) k_scan2(
        const int* __restrict__ bsum, int* __restrict__ bpre) {
    __shared__ int sh[512];
    int t = threadIdx.x;
    int v = (t < SCAN_NBLK) ? bsum[t] : 0;
    sh[t] = v;
    __syncthreads();
    for (int d = 1; d < 512; d <<= 1) {
        int u = (t >= d) ? sh[t - d] : 0;
        __syncthreads();
        sh[t] += u;
        __syncthreads();
    }
    if (t < SCAN_NBLK) bpre[t] = sh[t] - v;   // exclusive
}

__global__ void __launch_bounds__(256) k_scan3(
        const int* __restrict__ deg, const int* __restrict__ bpre,
        int* __restrict__ off) {
    __shared__ int sh[256];
    int t = threadIdx.x;
    int g = blockIdx.x * 256 + t;
    int v = (g < N_NODES) ? deg[g] : 0;
    sh[t] = v;
    __syncthreads();
    for (int d = 1; d < 256; d <<= 1) {
        int u = (t >= d) ? sh[t - d] : 0;
        __syncthreads();
        sh[t] += u;
        __syncthreads();
    }
    int incl = sh[t];
    int base = bpre[blockIdx.x];
    if (g < N_NODES) off[g] = base + incl - v;
    if (g == N_NODES - 1) off[N_NODES] = base + incl;
}

// Scatter ONLY perm (one random 4B stream instead of two; psrc is produced
// sequentially by k_gather below).
__global__ void __launch_bounds__(256) k_scatter(
        const int* __restrict__ dst,
        int* __restrict__ cursor, int* __restrict__ perm) {
    int e = blockIdx.x * 256 + threadIdx.x;
    if (e >= N_EDGES) return;
    int d = dst[e];
    int pos = atomicAdd(&cursor[d], 1);
    perm[pos] = e;
}

// Gather src + eattr rows into CSR (perm) order. Random READS (cacheable),
// all writes sequential/coalesced.
__global__ void __launch_bounds__(256) k_gather(
        const int* __restrict__ perm, const int* __restrict__ src,
        const float* __restrict__ eattr,
        int* __restrict__ psrc, float* __restrict__ ea_lin) {
    int pos = blockIdx.x * 256 + threadIdx.x;
    if (pos >= N_EDGES) return;
    int e = perm[pos];
    psrc[pos] = src[e];
    const float4* ap = reinterpret_cast<const float4*>(eattr + (size_t)e * F_EDGE);
    float4 a0 = ap[0], a1 = ap[1];
    float4* op = reinterpret_cast<float4*>(ea_lin + (size_t)pos * F_EDGE);
    op[0] = a0;
    op[1] = a1;
}

// ---- GENConv aggregation: one wave per destination node, lane = feature.
__global__ void __launch_bounds__(256) k_gen_agg(
        const float* __restrict__ h, const int* __restrict__ off,
        const int* __restrict__ psrc, const float* __restrict__ ea_lin,
        const float* __restrict__ eW, const float* __restrict__ eb,
        float* __restrict__ outb) {
    int n = blockIdx.x * 4 + (threadIdx.x >> 6);
    if (n >= N_NODES) return;
    int f = threadIdx.x & 63;
    float w[F_EDGE];
#pragma unroll
    for (int k = 0; k < F_EDGE; k++) w[k] = eW[k * HD + f];
    float bf = eb[f];
    int nu = __builtin_amdgcn_readfirstlane(n);
    int beg = off[nu], end = off[nu + 1];
    float den = 0.f, nm = 0.f;
    int i = beg;
    for (; i + 8 <= end; i += 8) {
        int s[8];
#pragma unroll
        for (int u = 0; u < 8; u++) s[u] = psrc[i + u];
        float hv[8];
#pragma unroll
        for (int u = 0; u < 8; u++) hv[u] = h[(size_t)s[u] * HD + f];
#pragma unroll
        for (int u = 0; u < 8; u++) {
            const float4* ap = reinterpret_cast<const float4*>(
                ea_lin + (size_t)(i + u) * F_EDGE);
            float4 a0 = ap[0], a1 = ap[1];
            float ea = bf + a0.x * w[0] + a0.y * w[1] + a0.z * w[2] + a0.w * w[3]
                          + a1.x * w[4] + a1.y * w[5] + a1.z * w[6] + a1.w * w[7];
            float m = fmaxf(hv[u] + ea, 0.f) + GEN_EPS;
            float ev = __expf(m);
            den += ev;
            nm += m * ev;
        }
    }
    for (; i < end; i++) {
        int s = psrc[i];
        const float4* ap = reinterpret_cast<const float4*>(
            ea_lin + (size_t)i * F_EDGE);
        float4 a0 = ap[0], a1 = ap[1];
        float hv = h[(size_t)s * HD + f];
        float ea = bf + a0.x * w[0] + a0.y * w[1] + a0.z * w[2] + a0.w * w[3]
                      + a1.x * w[4] + a1.y * w[5] + a1.z * w[6] + a1.w * w[7];
        float m = fmaxf(hv + ea, 0.f) + GEN_EPS;
        float ev = __expf(m);
        den += ev;
        nm += m * ev;
    }
    size_t idx = (size_t)n * HD + f;
    outb[idx] = h[idx] + nm / fmaxf(den, 1e-16f);
}

// ---- Fused MLP: h' = relu( relu(in@W1+b1) @ W2 + b2 ).
// One 64-node tile per block, 512 threads. Activation tiles stored TRANSPOSED
// ([f][n]) so per-f loads are ds_read_b128. hid never leaves LDS: kills the
// 102 MB global round-trip. LDS ~114 KB -> 1 block/CU (160 KB max).
__global__ void __launch_bounds__(512) k_mlp_fused(
        const float* __restrict__ inb,
        const float* __restrict__ W1, const float* __restrict__ b1,
        const float* __restrict__ W2, const float* __restrict__ b2,
        float* __restrict__ hout) {
    __shared__ float sW1[HD * HD2];    // 32 KB  [f][j] row-major
    __shared__ float sW2[HD2 * HD];    // 32 KB  [j][f2] row-major
    __shared__ float sb1[HD2];
    __shared__ float sb2[HD];
    __shared__ float sIn[HD][65];      // 16.25 KB [f][n]
    __shared__ float sHid[HD2][65];    // 32.5 KB  [j][n]
    int tid = threadIdx.x;
    int n0 = blockIdx.x * 64;
    for (int i = tid; i < HD * HD2; i += 512) {
        sW1[i] = W1[i];
        sW2[i] = W2[i];
    }
    if (tid < HD2) sb1[tid] = b1[tid];
    if (tid < HD) sb2[tid] = b2[tid];
    // stage input tile transposed: 64 nodes x 16 float4 = 1024 items
    for (int i = tid; i < 64 * 16; i += 512) {
        int n = i >> 4, fq = i & 15;
        int gn = n0 + n;
        float4 v = (gn < N_NODES)
            ? reinterpret_cast<const float4*>(inb + (size_t)gn * HD)[fq]
            : make_float4(0.f, 0.f, 0.f, 0.f);
        sIn[fq * 4 + 0][n] = v.x; sIn[fq * 4 + 1][n] = v.y;
        sIn[fq * 4 + 2][n] = v.z; sIn[fq * 4 + 3][n] = v.w;
    }
    __syncthreads();
    // stage 1: 64n x 128j, thread tile 4n x 4j
    {
        int ng = tid >> 5, jg = tid & 31;
        int nb = ng * 4, jb = jg * 4;
        float acc[4][4];
#pragma unroll
        for (int i = 0; i < 4; i++)
#pragma unroll
            for (int q = 0; q < 4; q++) acc[i][q] = sb1[jb + q];
#pragma unroll 4
        for (int f = 0; f < HD; f++) {
            float4 w = *reinterpret_cast<const float4*>(&sW1[f * HD2 + jb]);
            float4 xv = *reinterpret_cast<const float4*>(&sIn[f][nb]);
            float x[4] = {xv.x, xv.y, xv.z, xv.w};
#pragma unroll
            for (int i = 0; i < 4; i++) {
                acc[i][0] += x[i] * w.x;
                acc[i][1] += x[i] * w.y;
                acc[i][2] += x[i] * w.z;
                acc[i][3] += x[i] * w.w;
            }
        }
#pragma unroll
        for (int q = 0; q < 4; q++) {
            float4 o;
            o.x = fmaxf(acc[0][q], 0.f);
            o.y = fmaxf(acc[1][q], 0.f);
            o.z = fmaxf(acc[2][q], 0.f);
            o.w = fmaxf(acc[3][q], 0.f);
            *reinterpret_cast<float4*>(&sHid[jb + q][nb]) = o;
        }
    }
    __syncthreads();
    // stage 2: 64n x 64j, thread tile 2n x 4j
    {
        int ng = tid >> 4, jg = tid & 15;
        int nb = ng * 2, jb = jg * 4;
        float acc[2][4];
#pragma unroll
        for (int i = 0; i < 2; i++)
#pragma unroll
            for (int q = 0; q < 4; q++) acc[i][q] = sb2[jb + q];
#pragma unroll 4
        for (int f2 = 0; f2 < HD2; f2++) {
            float4 w = *reinterpret_cast<const float4*>(&sW2[f2 * HD + jb]);
            float x0 = sHid[f2][nb], x1 = sHid[f2][nb + 1];
            acc[0][0] += x0 * w.x; acc[0][1] += x0 * w.y;
            acc[0][2] += x0 * w.z; acc[0][3] += x0 * w.w;
            acc[1][0] += x1 * w.x; acc[1][1] += x1 * w.y;
            acc[1][2] += x1 * w.z; acc[1][3] += x1 * w.w;
        }
#pragma unroll
        for (int i = 0; i < 2; i++) {
            int gn = n0 + nb + i;
            if (gn < N_NODES) {
                float4 o;
                o.x = fmaxf(acc[i][0], 0.f);
                o.y = fmaxf(acc[i][1], 0.f);
                o.z = fmaxf(acc[i][2], 0.f);
                o.w = fmaxf(acc[i][3], 0.f);
                *reinterpret_cast<float4*>(hout + (size_t)gn * HD + jb) = o;
            }
        }
    }
}

// batch is sorted -> graph g owns contiguous node range [gstart[g], gstart[g+1]).
__global__ void __launch_bounds__(256) k_gstart(
        const int* __restrict__ batch, int* __restrict__ gstart) {
    int g = blockIdx.x * 256 + threadIdx.x;
    if (g > N_GRAPHS) return;
    int lo = 0, hi = N_NODES;
    while (lo < hi) {
        int mid = (lo + hi) >> 1;
        if (batch[mid] < g) lo = mid + 1; else hi = mid;
    }
    gstart[g] = lo;
}

// One wave per graph, lane = feature: pooled[g][f] = mean over node range.
__global__ void __launch_bounds__(256) k_pool(
        const float* __restrict__ h, const int* __restrict__ gstart,
        float* __restrict__ pooled) {
    int g = blockIdx.x * 4 + (threadIdx.x >> 6);
    if (g >= N_GRAPHS) return;
    int f = threadIdx.x & 63;
    int b = gstart[g], e = gstart[g + 1];
    float s = 0.f;
    for (int n = b; n < e; n++) s += h[(size_t)n * HD + f];
    float cnt = fmaxf((float)(e - b), 1.f);
    pooled[(size_t)g * HD + f] = s / cnt;
}

__global__ void __launch_bounds__(64) k_head(
        const float* __restrict__ pooled, const float* __restrict__ gattr,
        const float* __restrict__ d1W, const float* __restrict__ d1b,
        const float* __restrict__ d2W, const float* __restrict__ d2b,
        const float* __restrict__ oW, const float* __restrict__ ob,
        float* __restrict__ out) {
    int g = blockIdx.x;
    __shared__ float si[HD + F_GRAPH];
    __shared__ float s1[32], s2[32];
    int t = threadIdx.x;
    if (t < HD) si[t] = pooled[(size_t)g * HD + t];
    if (t < F_GRAPH) si[HD + t] = gattr[(size_t)g * F_GRAPH + t];
    __syncthreads();
    if (t < 32) {
        float acc = d1b[t];
        for (int i = 0; i < HD + F_GRAPH; i++) acc += si[i] * d1W[i * 32 + t];
        s1[t] = fmaxf(acc, 0.f);
    }
    __syncthreads();
    if (t < 32) {
        float acc = d2b[t];
        for (int i = 0; i < 32; i++) acc += s1[i] * d2W[i * 32 + t];
        s2[t] = fmaxf(acc, 0.f);
    }
    __syncthreads();
    if (t == 0) {
        float acc = ob[0];
        for (int i = 0; i < 32; i++) acc += s2[i] * oW[i];
        out[g] = 1.f / (1.f + __expf(-acc));
    }
}

extern "C" void kernel_launch(void* const* d_in, const int* in_sizes, int n_in,
                              void* d_out, int out_size, void* d_ws, size_t ws_size,
                              hipStream_t stream) {
    const float* x     = (const float*)d_in[0];
    const float* eattr = (const float*)d_in[1];
    const float* gattr = (const float*)d_in[2];
    const int*   eidx  = (const int*)d_in[3];
    const int*   batch = (const int*)d_in[4];
    const float* nodeW = (const float*)d_in[5];
    const float* nodeb = (const float*)d_in[6];
    const float* edgeW = (const float*)d_in[7];
    const float* edgeb = (const float*)d_in[8];
    const float* cW1[3] = {(const float*)d_in[9],  (const float*)d_in[13], (const float*)d_in[17]};
    const float* cb1[3] = {(const float*)d_in[10], (const float*)d_in[14], (const float*)d_in[18]};
    const float* cW2[3] = {(const float*)d_in[11], (const float*)d_in[15], (const float*)d_in[19]};
    const float* cb2[3] = {(const float*)d_in[12], (const float*)d_in[16], (const float*)d_in[20]};
    const float* d1W = (const float*)d_in[21];
    const float* d1b = (const float*)d_in[22];
    const float* d2W = (const float*)d_in[23];
    const float* d2b = (const float*)d_in[24];
    const float* oW  = (const float*)d_in[25];
    const float* ob  = (const float*)d_in[26];

    const int* src = eidx;
    const int* dst = eidx + N_EDGES;

    // workspace layout
    char* p = (char*)d_ws;
    float* h      = (float*)p; p += (size_t)N_NODES * HD * 4;       // 25.6 MB
    float* outb   = (float*)p; p += (size_t)N_NODES * HD * 4;       // 25.6 MB
    float* ea_lin = (float*)p; p += (size_t)N_EDGES * F_EDGE * 4;   // 51.2 MB
    float* pooled = (float*)p; p += (size_t)N_GRAPHS * HD * 4;
    int*   off    = (int*)p;   p += (size_t)(N_NODES + 1) * 4;
    int*   cursor = (int*)p;   p += (size_t)N_NODES * 4;
    int*   gstart = (int*)p;   p += (size_t)(N_GRAPHS + 1) * 4;
    int*   perm   = (int*)p;   p += (size_t)N_EDGES * 4;
    int*   psrc   = (int*)p;   p += (size_t)N_EDGES * 4;
    int*   bsum   = (int*)p;   p += (size_t)(SCAN_NBLK + 1) * 4;
    int*   bpre   = (int*)p;   p += (size_t)(SCAN_NBLK + 1) * 4;

    const int EB = (N_EDGES + 255) / 256;
    const int NB64 = (N_NODES + 63) / 64;

    k_node_embed<<<(N_NODES * HD + 255) / 256, 256, 0, stream>>>(x, nodeW, nodeb, h);

    // CSR build
    hipMemsetAsync(cursor, 0, (size_t)N_NODES * 4, stream);
    k_hist<<<EB, 256, 0, stream>>>(dst, cursor);
    k_scan1<<<SCAN_NBLK, 256, 0, stream>>>(cursor, bsum);
    k_scan2<<<1, 512, 0, stream>>>(bsum, bpre);
    k_scan3<<<SCAN_NBLK, 256, 0, stream>>>(cursor, bpre, off);
    hipMemcpyAsync(cursor, off, (size_t)N_NODES * 4, hipMemcpyDeviceToDevice, stream);
    k_scatter<<<EB, 256, 0, stream>>>(dst, cursor, perm);
    k_gather<<<EB, 256, 0, stream>>>(perm, src, eattr, psrc, ea_lin);

    for (int l = 0; l < 3; l++) {
        k_gen_agg<<<(N_NODES + 3) / 4, 256, 0, stream>>>(
            h, off, psrc, ea_lin, edgeW, edgeb, outb);
        k_mlp_fused<<<NB64, 512, 0, stream>>>(
            outb, cW1[l], cb1[l], cW2[l], cb2[l], h);
    }

    k_gstart<<<(N_GRAPHS + 256) / 256, 256, 0, stream>>>(batch, gstart);
    k_pool<<<(N_GRAPHS + 3) / 4, 256, 0, stream>>>(h, gstart, pooled);
    k_head<<<N_GRAPHS, 64, 0, stream>>>(pooled, gattr,
                                        d1W, d1b, d2W, d2b, oW, ob,
                                        (float*)d_out);
}

// Round 8
// 923.891 us; speedup vs baseline: 1.0393x; 1.0393x over previous
//
#include <hip/hip_runtime.h>
#include <hip/hip_bf16.h>

#define N_NODES 100000
#define N_EDGES 1600000
#define N_GRAPHS 1024
#define F_NODE 16
#define F_EDGE 8
#define F_GRAPH 10
#define HD 64
#define HD2 128
#define GEN_EPS 1e-7f
#define SCAN_NBLK ((N_NODES + 255) / 256)   // 391

// h[n][f] = node_b[f] + sum_k x[n][k]*node_W[k][f]
__global__ void __launch_bounds__(256) k_node_embed(
        const float* __restrict__ x, const float* __restrict__ W,
        const float* __restrict__ b, float* __restrict__ h) {
    __shared__ float sW[F_NODE * HD];
    __shared__ float sb[HD];
    for (int i = threadIdx.x; i < F_NODE * HD; i += 256) sW[i] = W[i];
    if (threadIdx.x < HD) sb[threadIdx.x] = b[threadIdx.x];
    __syncthreads();
    int t = blockIdx.x * 256 + threadIdx.x;
    if (t >= N_NODES * HD) return;
    int n = t >> 6, f = t & 63;
    const float* xr = x + (size_t)n * F_NODE;
    float acc = sb[f];
#pragma unroll
    for (int k = 0; k < F_NODE; k++) acc += xr[k] * sW[k * HD + f];
    h[t] = acc;
}

// ---- CSR build (once per launch, reused by all 3 conv layers) ----
__global__ void __launch_bounds__(256) k_hist(
        const int* __restrict__ dst, int* __restrict__ deg) {
    int e = blockIdx.x * 256 + threadIdx.x;
    if (e >= N_EDGES) return;
    atomicAdd(&deg[dst[e]], 1);
}

// Parallel exclusive scan, 3 phases.
__global__ void __launch_bounds__(256) k_scan1(
        const int* __restrict__ deg, int* __restrict__ bsum) {
    __shared__ int red[256];
    int t = threadIdx.x;
    int g = blockIdx.x * 256 + t;
    red[t] = (g < N_NODES) ? deg[g] : 0;
    __syncthreads();
    for (int s = 128; s > 0; s >>= 1) {
        if (t < s) red[t] += red[t + s];
        __syncthreads();
    }
    if (t == 0) bsum[blockIdx.x] = red[0];
}

__global__ void __launch_bounds__(512) k_scan2(
        const int* __restrict__ bsum, int* __restrict__ bpre) {
    __shared__ int sh[512];
    int t = threadIdx.x;
    int v = (t < SCAN_NBLK) ? bsum[t] : 0;
    sh[t] = v;
    __syncthreads();
    for (int d = 1; d < 512; d <<= 1) {
        int u = (t >= d) ? sh[t - d] : 0;
        __syncthreads();
        sh[t] += u;
        __syncthreads();
    }
    if (t < SCAN_NBLK) bpre[t] = sh[t] - v;   // exclusive
}

__global__ void __launch_bounds__(256) k_scan3(
        const int* __restrict__ deg, const int* __restrict__ bpre,
        int* __restrict__ off) {
    __shared__ int sh[256];
    int t = threadIdx.x;
    int g = blockIdx.x * 256 + t;
    int v = (g < N_NODES) ? deg[g] : 0;
    sh[t] = v;
    __syncthreads();
    for (int d = 1; d < 256; d <<= 1) {
        int u = (t >= d) ? sh[t - d] : 0;
        __syncthreads();
        sh[t] += u;
        __syncthreads();
    }
    int incl = sh[t];
    int base = bpre[blockIdx.x];
    if (g < N_NODES) off[g] = base + incl - v;
    if (g == N_NODES - 1) off[N_NODES] = base + incl;
}

// Combined scatter: TWO independent random stores per thread (perm+psrc).
// Measured at the random-write-through roofline (~106us); splitting it
// halves write MLP and made it latency-bound (r7 regression).
__global__ void __launch_bounds__(256) k_scatter(
        const int* __restrict__ src, const int* __restrict__ dst,
        int* __restrict__ cursor, int* __restrict__ perm,
        int* __restrict__ psrc) {
    int e = blockIdx.x * 256 + threadIdx.x;
    if (e >= N_EDGES) return;
    int d = dst[e];
    int pos = atomicAdd(&cursor[d], 1);
    perm[pos] = e;
    psrc[pos] = src[e];
}

// Gather eattr rows into CSR (perm) order so agg layers stream them.
__global__ void __launch_bounds__(256) k_gather_ea(
        const int* __restrict__ perm, const float* __restrict__ eattr,
        float* __restrict__ ea_lin) {
    long long t = (long long)blockIdx.x * 256 + threadIdx.x;
    if (t >= (long long)N_EDGES * F_EDGE) return;
    int i = (int)(t >> 3), c = (int)(t & 7);
    int e = perm[i];
    ea_lin[(size_t)i * F_EDGE + c] = eattr[(size_t)e * F_EDGE + c];
}

// ---- GENConv aggregation: one wave per destination node, lane = feature.
__global__ void __launch_bounds__(256) k_gen_agg(
        const float* __restrict__ h, const int* __restrict__ off,
        const int* __restrict__ psrc, const float* __restrict__ ea_lin,
        const float* __restrict__ eW, const float* __restrict__ eb,
        float* __restrict__ outb) {
    int n = blockIdx.x * 4 + (threadIdx.x >> 6);
    if (n >= N_NODES) return;
    int f = threadIdx.x & 63;
    float w[F_EDGE];
#pragma unroll
    for (int k = 0; k < F_EDGE; k++) w[k] = eW[k * HD + f];
    float bf = eb[f];
    int nu = __builtin_amdgcn_readfirstlane(n);
    int beg = off[nu], end = off[nu + 1];
    float den = 0.f, nm = 0.f;
    int i = beg;
    for (; i + 8 <= end; i += 8) {
        int s[8];
#pragma unroll
        for (int u = 0; u < 8; u++) s[u] = psrc[i + u];
        float hv[8];
#pragma unroll
        for (int u = 0; u < 8; u++) hv[u] = h[(size_t)s[u] * HD + f];
#pragma unroll
        for (int u = 0; u < 8; u++) {
            const float4* ap = reinterpret_cast<const float4*>(
                ea_lin + (size_t)(i + u) * F_EDGE);
            float4 a0 = ap[0], a1 = ap[1];
            float ea = bf + a0.x * w[0] + a0.y * w[1] + a0.z * w[2] + a0.w * w[3]
                          + a1.x * w[4] + a1.y * w[5] + a1.z * w[6] + a1.w * w[7];
            float m = fmaxf(hv[u] + ea, 0.f) + GEN_EPS;
            float ev = __expf(m);
            den += ev;
            nm += m * ev;
        }
    }
    for (; i < end; i++) {
        int s = psrc[i];
        const float4* ap = reinterpret_cast<const float4*>(
            ea_lin + (size_t)i * F_EDGE);
        float4 a0 = ap[0], a1 = ap[1];
        float hv = h[(size_t)s * HD + f];
        float ea = bf + a0.x * w[0] + a0.y * w[1] + a0.z * w[2] + a0.w * w[3]
                      + a1.x * w[4] + a1.y * w[5] + a1.z * w[6] + a1.w * w[7];
        float m = fmaxf(hv + ea, 0.f) + GEN_EPS;
        float ev = __expf(m);
        den += ev;
        nm += m * ev;
    }
    size_t idx = (size_t)n * HD + f;
    outb[idx] = h[idx] + nm / fmaxf(den, 1e-16f);
}

// ---- MLP stage 1: hid[n][j] = relu(in[n][:] @ W1[:, j] + b1[j]), K=64, J=128.
// Activation tile TRANSPOSED [f][n] -> per-f activation loads are 2x b128
// instead of 8x b32. Thread tile 8n x 4j. LDS ~50 KB -> 3 blocks/CU.
__global__ void __launch_bounds__(256) k_mlp1(
        const float* __restrict__ inb,
        const float* __restrict__ W1, const float* __restrict__ b1,
        float* __restrict__ hid) {
    __shared__ float sIn[HD][68];      // [f][n], 17.4 KB (stride 272B, 16B-aligned)
    __shared__ float sW1[HD * HD2];    // 32 KB
    __shared__ float sb1[HD2];
    int tid = threadIdx.x;
    int n0 = blockIdx.x * 64;
    for (int i = tid; i < HD * HD2; i += 256) sW1[i] = W1[i];
    if (tid < HD2) sb1[tid] = b1[tid];
    for (int i = tid; i < 64 * 16; i += 256) {
        int n = i >> 4, fq = i & 15;
        int gn = n0 + n;
        float4 v = (gn < N_NODES)
            ? reinterpret_cast<const float4*>(inb + (size_t)gn * HD)[fq]
            : make_float4(0.f, 0.f, 0.f, 0.f);
        sIn[fq * 4 + 0][n] = v.x; sIn[fq * 4 + 1][n] = v.y;
        sIn[fq * 4 + 2][n] = v.z; sIn[fq * 4 + 3][n] = v.w;
    }
    __syncthreads();
    int ng = tid >> 5, jg = tid & 31;
    int nb = ng * 8, jb = jg * 4;
    float acc[8][4];
#pragma unroll
    for (int i = 0; i < 8; i++)
#pragma unroll
        for (int q = 0; q < 4; q++) acc[i][q] = sb1[jb + q];
#pragma unroll 2
    for (int f = 0; f < HD; f++) {
        float4 w  = *reinterpret_cast<const float4*>(&sW1[f * HD2 + jb]);
        float4 x0 = *reinterpret_cast<const float4*>(&sIn[f][nb]);
        float4 x1 = *reinterpret_cast<const float4*>(&sIn[f][nb + 4]);
        float xv[8] = {x0.x, x0.y, x0.z, x0.w, x1.x, x1.y, x1.z, x1.w};
#pragma unroll
        for (int i = 0; i < 8; i++) {
            acc[i][0] += xv[i] * w.x;
            acc[i][1] += xv[i] * w.y;
            acc[i][2] += xv[i] * w.z;
            acc[i][3] += xv[i] * w.w;
        }
    }
#pragma unroll
    for (int i = 0; i < 8; i++) {
        int gn = n0 + nb + i;
        if (gn < N_NODES) {
            float4 o;
            o.x = fmaxf(acc[i][0], 0.f);
            o.y = fmaxf(acc[i][1], 0.f);
            o.z = fmaxf(acc[i][2], 0.f);
            o.w = fmaxf(acc[i][3], 0.f);
            *reinterpret_cast<float4*>(hid + (size_t)gn * HD2 + jb) = o;
        }
    }
}

// ---- MLP stage 2: h'[n][j] = relu(hid[n][:] @ W2[:, j] + b2[j]), K=128, J=64.
// Transposed activation tile [f2][n]; thread tile 4n x 4j. LDS ~67 KB -> 2 blocks/CU.
__global__ void __launch_bounds__(256) k_mlp2(
        const float* __restrict__ hid,
        const float* __restrict__ W2, const float* __restrict__ b2,
        float* __restrict__ hout) {
    __shared__ float sH[HD2][68];      // [f2][n], 34.8 KB
    __shared__ float sW2[HD2 * HD];    // 32 KB
    __shared__ float sb2[HD];
    int tid = threadIdx.x;
    int n0 = blockIdx.x * 64;
    for (int i = tid; i < HD2 * HD; i += 256) sW2[i] = W2[i];
    if (tid < HD) sb2[tid] = b2[tid];
    for (int i = tid; i < 64 * 32; i += 256) {
        int n = i >> 5, fq = i & 31;
        int gn = n0 + n;
        float4 v = (gn < N_NODES)
            ? reinterpret_cast<const float4*>(hid + (size_t)gn * HD2)[fq]
            : make_float4(0.f, 0.f, 0.f, 0.f);
        sH[fq * 4 + 0][n] = v.x; sH[fq * 4 + 1][n] = v.y;
        sH[fq * 4 + 2][n] = v.z; sH[fq * 4 + 3][n] = v.w;
    }
    __syncthreads();
    int ng = tid >> 4, jg = tid & 15;
    int nb = ng * 4, jb = jg * 4;
    float acc[4][4];
#pragma unroll
    for (int i = 0; i < 4; i++)
#pragma unroll
        for (int q = 0; q < 4; q++) acc[i][q] = sb2[jb + q];
#pragma unroll 2
    for (int f2 = 0; f2 < HD2; f2++) {
        float4 w = *reinterpret_cast<const float4*>(&sW2[f2 * HD + jb]);
        float4 x = *reinterpret_cast<const float4*>(&sH[f2][nb]);
        float xv[4] = {x.x, x.y, x.z, x.w};
#pragma unroll
        for (int i = 0; i < 4; i++) {
            acc[i][0] += xv[i] * w.x;
            acc[i][1] += xv[i] * w.y;
            acc[i][2] += xv[i] * w.z;
            acc[i][3] += xv[i] * w.w;
        }
    }
#pragma unroll
    for (int i = 0; i < 4; i++) {
        int gn = n0 + nb + i;
        if (gn < N_NODES) {
            float4 o;
            o.x = fmaxf(acc[i][0], 0.f);
            o.y = fmaxf(acc[i][1], 0.f);
            o.z = fmaxf(acc[i][2], 0.f);
            o.w = fmaxf(acc[i][3], 0.f);
            *reinterpret_cast<float4*>(hout + (size_t)gn * HD + jb) = o;
        }
    }
}

// batch is sorted -> graph g owns contiguous node range [gstart[g], gstart[g+1]).
__global__ void __launch_bounds__(256) k_gstart(
        const int* __restrict__ batch, int* __restrict__ gstart) {
    int g = blockIdx.x * 256 + threadIdx.x;
    if (g > N_GRAPHS) return;
    int lo = 0, hi = N_NODES;
    while (lo < hi) {
        int mid = (lo + hi) >> 1;
        if (batch[mid] < g) lo = mid + 1; else hi = mid;
    }
    gstart[g] = lo;
}

// One wave per graph, lane = feature: pooled[g][f] = mean over node range.
__global__ void __launch_bounds__(256) k_pool(
        const float* __restrict__ h, const int* __restrict__ gstart,
        float* __restrict__ pooled) {
    int g = blockIdx.x * 4 + (threadIdx.x >> 6);
    if (g >= N_GRAPHS) return;
    int f = threadIdx.x & 63;
    int b = gstart[g], e = gstart[g + 1];
    float s = 0.f;
    for (int n = b; n < e; n++) s += h[(size_t)n * HD + f];
    float cnt = fmaxf((float)(e - b), 1.f);
    pooled[(size_t)g * HD + f] = s / cnt;
}

__global__ void __launch_bounds__(64) k_head(
        const float* __restrict__ pooled, const float* __restrict__ gattr,
        const float* __restrict__ d1W, const float* __restrict__ d1b,
        const float* __restrict__ d2W, const float* __restrict__ d2b,
        const float* __restrict__ oW, const float* __restrict__ ob,
        float* __restrict__ out) {
    int g = blockIdx.x;
    __shared__ float si[HD + F_GRAPH];
    __shared__ float s1[32], s2[32];
    int t = threadIdx.x;
    if (t < HD) si[t] = pooled[(size_t)g * HD + t];
    if (t < F_GRAPH) si[HD + t] = gattr[(size_t)g * F_GRAPH + t];
    __syncthreads();
    if (t < 32) {
        float acc = d1b[t];
        for (int i = 0; i < HD + F_GRAPH; i++) acc += si[i] * d1W[i * 32 + t];
        s1[t] = fmaxf(acc, 0.f);
    }
    __syncthreads();
    if (t < 32) {
        float acc = d2b[t];
        for (int i = 0; i < 32; i++) acc += s1[i] * d2W[i * 32 + t];
        s2[t] = fmaxf(acc, 0.f);
    }
    __syncthreads();
    if (t == 0) {
        float acc = ob[0];
        for (int i = 0; i < 32; i++) acc += s2[i] * oW[i];
        out[g] = 1.f / (1.f + __expf(-acc));
    }
}

extern "C" void kernel_launch(void* const* d_in, const int* in_sizes, int n_in,
                              void* d_out, int out_size, void* d_ws, size_t ws_size,
                              hipStream_t stream) {
    const float* x     = (const float*)d_in[0];
    const float* eattr = (const float*)d_in[1];
    const float* gattr = (const float*)d_in[2];
    const int*   eidx  = (const int*)d_in[3];
    const int*   batch = (const int*)d_in[4];
    const float* nodeW = (const float*)d_in[5];
    const float* nodeb = (const float*)d_in[6];
    const float* edgeW = (const float*)d_in[7];
    const float* edgeb = (const float*)d_in[8];
    const float* cW1[3] = {(const float*)d_in[9],  (const float*)d_in[13], (const float*)d_in[17]};
    const float* cb1[3] = {(const float*)d_in[10], (const float*)d_in[14], (const float*)d_in[18]};
    const float* cW2[3] = {(const float*)d_in[11], (const float*)d_in[15], (const float*)d_in[19]};
    const float* cb2[3] = {(const float*)d_in[12], (const float*)d_in[16], (const float*)d_in[20]};
    const float* d1W = (const float*)d_in[21];
    const float* d1b = (const float*)d_in[22];
    const float* d2W = (const float*)d_in[23];
    const float* d2b = (const float*)d_in[24];
    const float* oW  = (const float*)d_in[25];
    const float* ob  = (const float*)d_in[26];

    const int* src = eidx;
    const int* dst = eidx + N_EDGES;

    // workspace layout
    char* p = (char*)d_ws;
    float* h      = (float*)p; p += (size_t)N_NODES * HD * 4;       // 25.6 MB
    float* outb   = (float*)p; p += (size_t)N_NODES * HD * 4;       // 25.6 MB
    float* hid    = (float*)p; p += (size_t)N_NODES * HD2 * 4;      // 51.2 MB
    float* ea_lin = (float*)p; p += (size_t)N_EDGES * F_EDGE * 4;   // 51.2 MB
    float* pooled = (float*)p; p += (size_t)N_GRAPHS * HD * 4;
    int*   off    = (int*)p;   p += (size_t)(N_NODES + 1) * 4;
    int*   cursor = (int*)p;   p += (size_t)N_NODES * 4;
    int*   gstart = (int*)p;   p += (size_t)(N_GRAPHS + 1) * 4;
    int*   perm   = (int*)p;   p += (size_t)N_EDGES * 4;
    int*   psrc   = (int*)p;   p += (size_t)N_EDGES * 4;
    int*   bsum   = (int*)p;   p += (size_t)(SCAN_NBLK + 1) * 4;
    int*   bpre   = (int*)p;   p += (size_t)(SCAN_NBLK + 1) * 4;

    const int EB = (N_EDGES + 255) / 256;
    const int NB64 = (N_NODES + 63) / 64;

    k_node_embed<<<(N_NODES * HD + 255) / 256, 256, 0, stream>>>(x, nodeW, nodeb, h);

    // CSR build
    hipMemsetAsync(cursor, 0, (size_t)N_NODES * 4, stream);
    k_hist<<<EB, 256, 0, stream>>>(dst, cursor);
    k_scan1<<<SCAN_NBLK, 256, 0, stream>>>(cursor, bsum);
    k_scan2<<<1, 512, 0, stream>>>(bsum, bpre);
    k_scan3<<<SCAN_NBLK, 256, 0, stream>>>(cursor, bpre, off);
    hipMemcpyAsync(cursor, off, (size_t)N_NODES * 4, hipMemcpyDeviceToDevice, stream);
    k_scatter<<<EB, 256, 0, stream>>>(src, dst, cursor, perm, psrc);
    k_gather_ea<<<(int)(((long long)N_EDGES * F_EDGE + 255) / 256), 256, 0, stream>>>(
        perm, eattr, ea_lin);

    for (int l = 0; l < 3; l++) {
        k_gen_agg<<<(N_NODES + 3) / 4, 256, 0, stream>>>(
            h, off, psrc, ea_lin, edgeW, edgeb, outb);
        k_mlp1<<<NB64, 256, 0, stream>>>(outb, cW1[l], cb1[l], hid);
        k_mlp2<<<NB64, 256, 0, stream>>>(hid, cW2[l], cb2[l], h);
    }

    k_gstart<<<(N_GRAPHS + 256) / 256, 256, 0, stream>>>(batch, gstart);
    k_pool<<<(N_GRAPHS + 3) / 4, 256, 0, stream>>>(h, gstart, pooled);
    k_head<<<N_GRAPHS, 64, 0, stream>>>(pooled, gattr,
                                        d1W, d1b, d2W, d2b, oW, ob,
                                        (float*)d_out);
}

// Round 9
// 852.789 us; speedup vs baseline: 1.1260x; 1.0834x over previous
//
#include <hip/hip_runtime.h>
#include <hip/hip_bf16.h>

#define N_NODES 100000
#define N_EDGES 1600000
#define N_GRAPHS 1024
#define F_NODE 16
#define F_EDGE 8
#define F_GRAPH 10
#define HD 64
#define HD2 128
#define GEN_EPS 1e-7f
#define SCAN_NBLK ((N_NODES + 255) / 256)   // 391

// h[n][f] = node_b[f] + sum_k x[n][k]*node_W[k][f]
__global__ void __launch_bounds__(256) k_node_embed(
        const float* __restrict__ x, const float* __restrict__ W,
        const float* __restrict__ b, float* __restrict__ h) {
    __shared__ float sW[F_NODE * HD];
    __shared__ float sb[HD];
    for (int i = threadIdx.x; i < F_NODE * HD; i += 256) sW[i] = W[i];
    if (threadIdx.x < HD) sb[threadIdx.x] = b[threadIdx.x];
    __syncthreads();
    int t = blockIdx.x * 256 + threadIdx.x;
    if (t >= N_NODES * HD) return;
    int n = t >> 6, f = t & 63;
    const float* xr = x + (size_t)n * F_NODE;
    float acc = sb[f];
#pragma unroll
    for (int k = 0; k < F_NODE; k++) acc += xr[k] * sW[k * HD + f];
    h[t] = acc;
}

// ---- CSR build (once per launch, reused by all 3 conv layers) ----
__global__ void __launch_bounds__(256) k_hist(
        const int* __restrict__ dst, int* __restrict__ deg) {
    int e = blockIdx.x * 256 + threadIdx.x;
    if (e >= N_EDGES) return;
    atomicAdd(&deg[dst[e]], 1);
}

// Parallel exclusive scan, 3 phases.
__global__ void __launch_bounds__(256) k_scan1(
        const int* __restrict__ deg, int* __restrict__ bsum) {
    __shared__ int red[256];
    int t = threadIdx.x;
    int g = blockIdx.x * 256 + t;
    red[t] = (g < N_NODES) ? deg[g] : 0;
    __syncthreads();
    for (int s = 128; s > 0; s >>= 1) {
        if (t < s) red[t] += red[t + s];
        __syncthreads();
    }
    if (t == 0) bsum[blockIdx.x] = red[0];
}

__global__ void __launch_bounds__(512) k_scan2(
        const int* __restrict__ bsum, int* __restrict__ bpre) {
    __shared__ int sh[512];
    int t = threadIdx.x;
    int v = (t < SCAN_NBLK) ? bsum[t] : 0;
    sh[t] = v;
    __syncthreads();
    for (int d = 1; d < 512; d <<= 1) {
        int u = (t >= d) ? sh[t - d] : 0;
        __syncthreads();
        sh[t] += u;
        __syncthreads();
    }
    if (t < SCAN_NBLK) bpre[t] = sh[t] - v;   // exclusive
}

// Writes both off[] and cursor[] (cursor = working copy for scatter),
// removing the d2d memcpy. deg/cur alias-safe: per-thread read-then-write.
__global__ void __launch_bounds__(256) k_scan3(
        const int* deg, const int* __restrict__ bpre,
        int* __restrict__ off, int* cur) {
    __shared__ int sh[256];
    int t = threadIdx.x;
    int g = blockIdx.x * 256 + t;
    int v = (g < N_NODES) ? deg[g] : 0;
    sh[t] = v;
    __syncthreads();
    for (int d = 1; d < 256; d <<= 1) {
        int u = (t >= d) ? sh[t - d] : 0;
        __syncthreads();
        sh[t] += u;
        __syncthreads();
    }
    int incl = sh[t];
    int base = bpre[blockIdx.x];
    if (g < N_NODES) {
        off[g] = base + incl - v;
        cur[g] = base + incl - v;
    }
    if (g == N_NODES - 1) off[N_NODES] = base + incl;
}

// Fused scatter: per edge, one atomic + psrc store + 32B eattr-row store
// (3 independent random writes in flight per thread — the R8-measured
// roofline structure). Eliminates perm[] and the separate gather pass.
__global__ void __launch_bounds__(256) k_scatter(
        const int* __restrict__ src, const int* __restrict__ dst,
        const float* __restrict__ eattr,
        int* __restrict__ cursor, int* __restrict__ psrc,
        float* __restrict__ ea_lin) {
    int e = blockIdx.x * 256 + threadIdx.x;
    if (e >= N_EDGES) return;
    int d = dst[e];
    const float4* ap = reinterpret_cast<const float4*>(eattr + (size_t)e * F_EDGE);
    float4 a0 = ap[0], a1 = ap[1];          // coalesced 32B read
    int s = src[e];
    int pos = atomicAdd(&cursor[d], 1);
    psrc[pos] = s;
    float4* op = reinterpret_cast<float4*>(ea_lin + (size_t)pos * F_EDGE);
    op[0] = a0;                              // full 32B sector payload
    op[1] = a1;
}

// ---- GENConv aggregation: one wave per destination node, lane = feature.
__global__ void __launch_bounds__(256) k_gen_agg(
        const float* __restrict__ h, const int* __restrict__ off,
        const int* __restrict__ psrc, const float* __restrict__ ea_lin,
        const float* __restrict__ eW, const float* __restrict__ eb,
        float* __restrict__ outb) {
    int n = blockIdx.x * 4 + (threadIdx.x >> 6);
    if (n >= N_NODES) return;
    int f = threadIdx.x & 63;
    float w[F_EDGE];
#pragma unroll
    for (int k = 0; k < F_EDGE; k++) w[k] = eW[k * HD + f];
    float bf = eb[f];
    int nu = __builtin_amdgcn_readfirstlane(n);
    int beg = off[nu], end = off[nu + 1];
    float den = 0.f, nm = 0.f;
    int i = beg;
    for (; i + 8 <= end; i += 8) {
        int s[8];
#pragma unroll
        for (int u = 0; u < 8; u++) s[u] = psrc[i + u];
        float hv[8];
#pragma unroll
        for (int u = 0; u < 8; u++) hv[u] = h[(size_t)s[u] * HD + f];
#pragma unroll
        for (int u = 0; u < 8; u++) {
            const float4* ap = reinterpret_cast<const float4*>(
                ea_lin + (size_t)(i + u) * F_EDGE);
            float4 a0 = ap[0], a1 = ap[1];
            float ea = bf + a0.x * w[0] + a0.y * w[1] + a0.z * w[2] + a0.w * w[3]
                          + a1.x * w[4] + a1.y * w[5] + a1.z * w[6] + a1.w * w[7];
            float m = fmaxf(hv[u] + ea, 0.f) + GEN_EPS;
            float ev = __expf(m);
            den += ev;
            nm += m * ev;
        }
    }
    for (; i < end; i++) {
        int s = psrc[i];
        const float4* ap = reinterpret_cast<const float4*>(
            ea_lin + (size_t)i * F_EDGE);
        float4 a0 = ap[0], a1 = ap[1];
        float hv = h[(size_t)s * HD + f];
        float ea = bf + a0.x * w[0] + a0.y * w[1] + a0.z * w[2] + a0.w * w[3]
                      + a1.x * w[4] + a1.y * w[5] + a1.z * w[6] + a1.w * w[7];
        float m = fmaxf(hv + ea, 0.f) + GEN_EPS;
        float ev = __expf(m);
        den += ev;
        nm += m * ev;
    }
    size_t idx = (size_t)n * HD + f;
    outb[idx] = h[idx] + nm / fmaxf(den, 1e-16f);
}

// ---- MLP stage 1: hid[n][j] = relu(in[n][:] @ W1[:, j] + b1[j]), K=64, J=128.
// Transposed [f][n] activation tile. Staging: lane = node -> lanes sweep n
// within one row = conflict-free writes (the R8 staging had lanes sweeping f
// at row-stride 272 -> 2 banks -> 8-way conflicts). Reads: b128 x + b128 w.
__global__ void __launch_bounds__(256) k_mlp1(
        const float* __restrict__ inb,
        const float* __restrict__ W1, const float* __restrict__ b1,
        float* __restrict__ hid) {
    __shared__ float sIn[HD][68];      // [f][n], 17.4 KB
    __shared__ float sW1[HD * HD2];    // 32 KB
    __shared__ float sb1[HD2];
    int tid = threadIdx.x;
    int n0 = blockIdx.x * 64;
    for (int i = tid; i < HD * HD2; i += 256) sW1[i] = W1[i];
    if (tid < HD2) sb1[tid] = b1[tid];
    {
        int n = tid & 63;
        int q = tid >> 6;              // 0..3
        int gn = n0 + n;
#pragma unroll
        for (int g = 0; g < 4; g++) {
            int fqi = g * 4 + q;       // 0..15
            float4 v = (gn < N_NODES)
                ? reinterpret_cast<const float4*>(inb + (size_t)gn * HD)[fqi]
                : make_float4(0.f, 0.f, 0.f, 0.f);
            sIn[fqi * 4 + 0][n] = v.x; sIn[fqi * 4 + 1][n] = v.y;
            sIn[fqi * 4 + 2][n] = v.z; sIn[fqi * 4 + 3][n] = v.w;
        }
    }
    __syncthreads();
    int ng = tid >> 5, jg = tid & 31;
    int nb = ng * 8, jb = jg * 4;
    float acc[8][4];
#pragma unroll
    for (int i = 0; i < 8; i++)
#pragma unroll
        for (int q = 0; q < 4; q++) acc[i][q] = sb1[jb + q];
#pragma unroll 2
    for (int f = 0; f < HD; f++) {
        float4 w  = *reinterpret_cast<const float4*>(&sW1[f * HD2 + jb]);
        float4 x0 = *reinterpret_cast<const float4*>(&sIn[f][nb]);
        float4 x1 = *reinterpret_cast<const float4*>(&sIn[f][nb + 4]);
        float xv[8] = {x0.x, x0.y, x0.z, x0.w, x1.x, x1.y, x1.z, x1.w};
#pragma unroll
        for (int i = 0; i < 8; i++) {
            acc[i][0] += xv[i] * w.x;
            acc[i][1] += xv[i] * w.y;
            acc[i][2] += xv[i] * w.z;
            acc[i][3] += xv[i] * w.w;
        }
    }
#pragma unroll
    for (int i = 0; i < 8; i++) {
        int gn = n0 + nb + i;
        if (gn < N_NODES) {
            float4 o;
            o.x = fmaxf(acc[i][0], 0.f);
            o.y = fmaxf(acc[i][1], 0.f);
            o.z = fmaxf(acc[i][2], 0.f);
            o.w = fmaxf(acc[i][3], 0.f);
            *reinterpret_cast<float4*>(hid + (size_t)gn * HD2 + jb) = o;
        }
    }
}

// ---- MLP stage 2: h'[n][j] = relu(hid[n][:] @ W2[:, j] + b2[j]), K=128, J=64.
// Same conflict-free transposed staging.
__global__ void __launch_bounds__(256) k_mlp2(
        const float* __restrict__ hid,
        const float* __restrict__ W2, const float* __restrict__ b2,
        float* __restrict__ hout) {
    __shared__ float sH[HD2][68];      // [f2][n], 34.8 KB
    __shared__ float sW2[HD2 * HD];    // 32 KB
    __shared__ float sb2[HD];
    int tid = threadIdx.x;
    int n0 = blockIdx.x * 64;
    for (int i = tid; i < HD2 * HD; i += 256) sW2[i] = W2[i];
    if (tid < HD) sb2[tid] = b2[tid];
    {
        int n = tid & 63;
        int q = tid >> 6;              // 0..3
        int gn = n0 + n;
#pragma unroll
        for (int g = 0; g < 8; g++) {
            int fqi = g * 4 + q;       // 0..31
            float4 v = (gn < N_NODES)
                ? reinterpret_cast<const float4*>(hid + (size_t)gn * HD2)[fqi]
                : make_float4(0.f, 0.f, 0.f, 0.f);
            sH[fqi * 4 + 0][n] = v.x; sH[fqi * 4 + 1][n] = v.y;
            sH[fqi * 4 + 2][n] = v.z; sH[fqi * 4 + 3][n] = v.w;
        }
    }
    __syncthreads();
    int ng = tid >> 4, jg = tid & 15;
    int nb = ng * 4, jb = jg * 4;
    float acc[4][4];
#pragma unroll
    for (int i = 0; i < 4; i++)
#pragma unroll
        for (int q = 0; q < 4; q++) acc[i][q] = sb2[jb + q];
#pragma unroll 2
    for (int f2 = 0; f2 < HD2; f2++) {
        float4 w = *reinterpret_cast<const float4*>(&sW2[f2 * HD + jb]);
        float4 x = *reinterpret_cast<const float4*>(&sH[f2][nb]);
        float xv[4] = {x.x, x.y, x.z, x.w};
#pragma unroll
        for (int i = 0; i < 4; i++) {
            acc[i][0] += xv[i] * w.x;
            acc[i][1] += xv[i] * w.y;
            acc[i][2] += xv[i] * w.z;
            acc[i][3] += xv[i] * w.w;
        }
    }
#pragma unroll
    for (int i = 0; i < 4; i++) {
        int gn = n0 + nb + i;
        if (gn < N_NODES) {
            float4 o;
            o.x = fmaxf(acc[i][0], 0.f);
            o.y = fmaxf(acc[i][1], 0.f);
            o.z = fmaxf(acc[i][2], 0.f);
            o.w = fmaxf(acc[i][3], 0.f);
            *reinterpret_cast<float4*>(hout + (size_t)gn * HD + jb) = o;
        }
    }
}

// batch is sorted -> graph g owns contiguous node range [gstart[g], gstart[g+1]).
__global__ void __launch_bounds__(256) k_gstart(
        const int* __restrict__ batch, int* __restrict__ gstart) {
    int g = blockIdx.x * 256 + threadIdx.x;
    if (g > N_GRAPHS) return;
    int lo = 0, hi = N_NODES;
    while (lo < hi) {
        int mid = (lo + hi) >> 1;
        if (batch[mid] < g) lo = mid + 1; else hi = mid;
    }
    gstart[g] = lo;
}

// One wave per graph, lane = feature: pooled[g][f] = mean over node range.
__global__ void __launch_bounds__(256) k_pool(
        const float* __restrict__ h, const int* __restrict__ gstart,
        float* __restrict__ pooled) {
    int g = blockIdx.x * 4 + (threadIdx.x >> 6);
    if (g >= N_GRAPHS) return;
    int f = threadIdx.x & 63;
    int b = gstart[g], e = gstart[g + 1];
    float s = 0.f;
    for (int n = b; n < e; n++) s += h[(size_t)n * HD + f];
    float cnt = fmaxf((float)(e - b), 1.f);
    pooled[(size_t)g * HD + f] = s / cnt;
}

__global__ void __launch_bounds__(64) k_head(
        const float* __restrict__ pooled, const float* __restrict__ gattr,
        const float* __restrict__ d1W, const float* __restrict__ d1b,
        const float* __restrict__ d2W, const float* __restrict__ d2b,
        const float* __restrict__ oW, const float* __restrict__ ob,
        float* __restrict__ out) {
    int g = blockIdx.x;
    __shared__ float si[HD + F_GRAPH];
    __shared__ float s1[32], s2[32];
    int t = threadIdx.x;
    if (t < HD) si[t] = pooled[(size_t)g * HD + t];
    if (t < F_GRAPH) si[HD + t] = gattr[(size_t)g * F_GRAPH + t];
    __syncthreads();
    if (t < 32) {
        float acc = d1b[t];
        for (int i = 0; i < HD + F_GRAPH; i++) acc += si[i] * d1W[i * 32 + t];
        s1[t] = fmaxf(acc, 0.f);
    }
    __syncthreads();
    if (t < 32) {
        float acc = d2b[t];
        for (int i = 0; i < 32; i++) acc += s1[i] * d2W[i * 32 + t];
        s2[t] = fmaxf(acc, 0.f);
    }
    __syncthreads();
    if (t == 0) {
        float acc = ob[0];
        for (int i = 0; i < 32; i++) acc += s2[i] * oW[i];
        out[g] = 1.f / (1.f + __expf(-acc));
    }
}

extern "C" void kernel_launch(void* const* d_in, const int* in_sizes, int n_in,
                              void* d_out, int out_size, void* d_ws, size_t ws_size,
                              hipStream_t stream) {
    const float* x     = (const float*)d_in[0];
    const float* eattr = (const float*)d_in[1];
    const float* gattr = (const float*)d_in[2];
    const int*   eidx  = (const int*)d_in[3];
    const int*   batch = (const int*)d_in[4];
    const float* nodeW = (const float*)d_in[5];
    const float* nodeb = (const float*)d_in[6];
    const float* edgeW = (const float*)d_in[7];
    const float* edgeb = (const float*)d_in[8];
    const float* cW1[3] = {(const float*)d_in[9],  (const float*)d_in[13], (const float*)d_in[17]};
    const float* cb1[3] = {(const float*)d_in[10], (const float*)d_in[14], (const float*)d_in[18]};
    const float* cW2[3] = {(const float*)d_in[11], (const float*)d_in[15], (const float*)d_in[19]};
    const float* cb2[3] = {(const float*)d_in[12], (const float*)d_in[16], (const float*)d_in[20]};
    const float* d1W = (const float*)d_in[21];
    const float* d1b = (const float*)d_in[22];
    const float* d2W = (const float*)d_in[23];
    const float* d2b = (const float*)d_in[24];
    const float* oW  = (const float*)d_in[25];
    const float* ob  = (const float*)d_in[26];

    const int* src = eidx;
    const int* dst = eidx + N_EDGES;

    // workspace layout
    char* p = (char*)d_ws;
    float* h      = (float*)p; p += (size_t)N_NODES * HD * 4;       // 25.6 MB
    float* outb   = (float*)p; p += (size_t)N_NODES * HD * 4;       // 25.6 MB
    float* hid    = (float*)p; p += (size_t)N_NODES * HD2 * 4;      // 51.2 MB
    float* ea_lin = (float*)p; p += (size_t)N_EDGES * F_EDGE * 4;   // 51.2 MB
    float* pooled = (float*)p; p += (size_t)N_GRAPHS * HD * 4;
    int*   off    = (int*)p;   p += (size_t)(N_NODES + 1) * 4;
    int*   cursor = (int*)p;   p += (size_t)N_NODES * 4;
    int*   gstart = (int*)p;   p += (size_t)(N_GRAPHS + 1) * 4;
    int*   psrc   = (int*)p;   p += (size_t)N_EDGES * 4;
    int*   bsum   = (int*)p;   p += (size_t)(SCAN_NBLK + 1) * 4;
    int*   bpre   = (int*)p;   p += (size_t)(SCAN_NBLK + 1) * 4;

    const int EB = (N_EDGES + 255) / 256;
    const int NB64 = (N_NODES + 63) / 64;

    k_node_embed<<<(N_NODES * HD + 255) / 256, 256, 0, stream>>>(x, nodeW, nodeb, h);

    // CSR build
    hipMemsetAsync(cursor, 0, (size_t)N_NODES * 4, stream);
    k_hist<<<EB, 256, 0, stream>>>(dst, cursor);
    k_scan1<<<SCAN_NBLK, 256, 0, stream>>>(cursor, bsum);
    k_scan2<<<1, 512, 0, stream>>>(bsum, bpre);
    k_scan3<<<SCAN_NBLK, 256, 0, stream>>>(cursor, bpre, off, cursor);
    k_scatter<<<EB, 256, 0, stream>>>(src, dst, eattr, cursor, psrc, ea_lin);

    for (int l = 0; l < 3; l++) {
        k_gen_agg<<<(N_NODES + 3) / 4, 256, 0, stream>>>(
            h, off, psrc, ea_lin, edgeW, edgeb, outb);
        k_mlp1<<<NB64, 256, 0, stream>>>(outb, cW1[l], cb1[l], hid);
        k_mlp2<<<NB64, 256, 0, stream>>>(hid, cW2[l], cb2[l], h);
    }

    k_gstart<<<(N_GRAPHS + 256) / 256, 256, 0, stream>>>(batch, gstart);
    k_pool<<<(N_GRAPHS + 3) / 4, 256, 0, stream>>>(h, gstart, pooled);
    k_head<<<N_GRAPHS, 64, 0, stream>>>(pooled, gattr,
                                        d1W, d1b, d2W, d2b, oW, ob,
                                        (float*)d_out);
}